// Round 1
// baseline (113.889 us; speedup 1.0000x reference)
//
#include <hip/hip_runtime.h>
#include <math.h>

#define CIN   3
#define COUT  16
#define DHW   64

// One thread per output voxel (n,d,h,w).
// ConvTranspose3d(k=3,s=2,p=1,op=1) + MaxPool3d(2,2) fused:
//   od = 2*id - 1 + kd  =>  for pooled voxel d (window od in {2d,2d+1}):
//     kd==1 -> even pos (pd=0), id=d
//     kd==0 -> odd  pos (pd=1), id=d+1
//     kd==2 -> odd  pos (pd=1), id=d
// Each of the 27 taps hits exactly one of the 8 pool positions.
__global__ __launch_bounds__(256) void fused_convt_pool_softmax_swish_max(
    const float* __restrict__ x,      // [N,CIN,64,64,64]
    const float* __restrict__ w,      // [CIN,COUT,3,3,3]
    const float* __restrict__ bias,   // [COUT]
    const float* __restrict__ sub,    // [COUT]
    float* __restrict__ out)          // [N,64,64,64]
{
    const int wv = threadIdx.x;                       // w coordinate, 0..63 (one wave = one row)
    const int h  = blockIdx.x * blockDim.y + threadIdx.y;
    const int d  = blockIdx.y;
    const int n  = blockIdx.z;

    // Load x neighborhood: xr[cin][dd][hh][ww], ww: 0 -> iw=w, 1 -> iw=w+1 (via shuffle)
    float xr[CIN][2][2][2];
    const size_t nbase = (size_t)n * CIN * DHW * DHW * DHW;
#pragma unroll
    for (int c = 0; c < CIN; ++c) {
#pragma unroll
        for (int dd = 0; dd < 2; ++dd) {
#pragma unroll
            for (int hh = 0; hh < 2; ++hh) {
                const int id = d + dd;
                const int ih = h + hh;
                float v = 0.0f;
                if (id < DHW && ih < DHW) {
                    v = x[nbase + (((size_t)c * DHW + id) * DHW + ih) * DHW + wv];
                }
                xr[c][dd][hh][0] = v;
                float v1 = __shfl_down(v, 1, 64);
                xr[c][dd][hh][1] = (wv == 63) ? 0.0f : v1;
            }
        }
    }

    float pooled[COUT];
#pragma unroll
    for (int co = 0; co < COUT; ++co) {
        float acc[2][2][2] = {{{0.0f,0.0f},{0.0f,0.0f}},{{0.0f,0.0f},{0.0f,0.0f}}};
#pragma unroll
        for (int c = 0; c < CIN; ++c) {
            const float* wp = w + ((size_t)c * COUT + co) * 27;
#pragma unroll
            for (int kd = 0; kd < 3; ++kd) {
                const int pd = (kd == 1) ? 0 : 1;
                const int dd = (kd == 0) ? 1 : 0;
#pragma unroll
                for (int kh = 0; kh < 3; ++kh) {
                    const int ph = (kh == 1) ? 0 : 1;
                    const int hh = (kh == 0) ? 1 : 0;
#pragma unroll
                    for (int kw = 0; kw < 3; ++kw) {
                        const int pw = (kw == 1) ? 0 : 1;
                        const int ww = (kw == 0) ? 1 : 0;
                        acc[pd][ph][pw] = fmaf(wp[kd * 9 + kh * 3 + kw],
                                               xr[c][dd][hh][ww],
                                               acc[pd][ph][pw]);
                    }
                }
            }
        }
        float mx = acc[0][0][0];
        mx = fmaxf(mx, acc[0][0][1]);
        mx = fmaxf(mx, acc[0][1][0]);
        mx = fmaxf(mx, acc[0][1][1]);
        mx = fmaxf(mx, acc[1][0][0]);
        mx = fmaxf(mx, acc[1][0][1]);
        mx = fmaxf(mx, acc[1][1][0]);
        mx = fmaxf(mx, acc[1][1][1]);
        pooled[co] = mx + bias[co];
    }

    // channel softmax
    float m = pooled[0];
#pragma unroll
    for (int co = 1; co < COUT; ++co) m = fmaxf(m, pooled[co]);
    float e[COUT];
    float s = 0.0f;
#pragma unroll
    for (int co = 0; co < COUT; ++co) {
        e[co] = __expf(pooled[co] - m);
        s += e[co];
    }
    const float inv = 1.0f / s;

    // subtract + swish + channel max
    float best = -3.402823466e+38f;
#pragma unroll
    for (int co = 0; co < COUT; ++co) {
        const float z  = fmaf(e[co], inv, -sub[co]);
        const float sw = z / (1.0f + __expf(-z));
        best = fmaxf(best, sw);
    }

    out[(((size_t)n * DHW + d) * DHW + h) * DHW + wv] = best;
}

extern "C" void kernel_launch(void* const* d_in, const int* in_sizes, int n_in,
                              void* d_out, int out_size, void* d_ws, size_t ws_size,
                              hipStream_t stream) {
    const float* x   = (const float*)d_in[0];
    const float* w   = (const float*)d_in[1];
    const float* b   = (const float*)d_in[2];
    const float* sub = (const float*)d_in[3];
    float* out = (float*)d_out;

    dim3 block(64, 4, 1);                 // one wave per W-row
    dim3 grid(DHW / 4, DHW, 4);          // (h-groups, d, n)
    fused_convt_pool_softmax_swish_max<<<grid, block, 0, stream>>>(x, w, b, sub, out);
}

// Round 2
// 107.740 us; speedup vs baseline: 1.0571x; 1.0571x over previous
//
#include <hip/hip_runtime.h>
#include <math.h>

#define CIN   3
#define COUT  16
#define DHW   64

// One thread per TWO output voxels (n,d,h,{2t,2t+1}).
// ConvTranspose3d(k=3,s=2,p=1,op=1) + MaxPool3d(2,2) fused:
//   od = 2*id - 1 + kd  =>  for pooled voxel d (window od in {2d,2d+1}):
//     kd==1 -> even pos (pd=0), id=d
//     kd==0 -> odd  pos (pd=1), id=d+1
//     kd==2 -> odd  pos (pd=1), id=d
// Each of the 27 taps hits exactly one of the 8 pool positions.
// __launch_bounds__(256,4): 128-VGPR cap so xr/acc/pooled stay register-resident
// (round-1 kernel was clamped to 32 VGPRs -> compiler re-materialized the x
// neighborhood every co iteration, ~2.6x instruction bloat).
__global__ __launch_bounds__(256, 4) void fused_convt_pool_softmax_swish_max(
    const float* __restrict__ x,      // [N,CIN,64,64,64]
    const float* __restrict__ w,      // [CIN,COUT,3,3,3]
    const float* __restrict__ bias,   // [COUT]
    const float* __restrict__ sub,    // [COUT]
    float* __restrict__ out)          // [N,64,64,64]
{
    const int tp = threadIdx.x;                      // w-pair index, 0..31
    const int h  = blockIdx.x * blockDim.y + threadIdx.y;
    const int d  = blockIdx.y;
    const int n  = blockIdx.z;
    const int w0 = tp * 2;                           // outputs w0, w0+1; inputs w0..w0+2

    // Load x neighborhood: xr[cin][dd][hh][iw-w0], iw in {w0, w0+1, w0+2}
    float xr[CIN][2][2][3];
    const size_t nbase = (size_t)n * CIN * DHW * DHW * DHW;
#pragma unroll
    for (int c = 0; c < CIN; ++c) {
#pragma unroll
        for (int dd = 0; dd < 2; ++dd) {
#pragma unroll
            for (int hh = 0; hh < 2; ++hh) {
                const int id = d + dd;
                const int ih = h + hh;
                float v0 = 0.0f, v1 = 0.0f, v2 = 0.0f;
                if (id < DHW && ih < DHW) {
                    const float* row = x + nbase + (((size_t)c * DHW + id) * DHW + ih) * DHW + w0;
                    const float2 a = *(const float2*)row;    // 8B-aligned (w0 even)
                    v0 = a.x;
                    v1 = a.y;
                    if (w0 + 2 < DHW) v2 = row[2];
                }
                xr[c][dd][hh][0] = v0;
                xr[c][dd][hh][1] = v1;
                xr[c][dd][hh][2] = v2;
            }
        }
    }

    float pooled[2][COUT];
#pragma unroll
    for (int co = 0; co < COUT; ++co) {
        float acc[2][2][2][2];                       // [voxel][pd][ph][pw]
#pragma unroll
        for (int v = 0; v < 2; ++v)
#pragma unroll
            for (int i = 0; i < 2; ++i)
#pragma unroll
                for (int j = 0; j < 2; ++j)
#pragma unroll
                    for (int k = 0; k < 2; ++k)
                        acc[v][i][j][k] = 0.0f;
#pragma unroll
        for (int c = 0; c < CIN; ++c) {
            const float* wp = w + ((size_t)(c * COUT + co)) * 27;
#pragma unroll
            for (int kd = 0; kd < 3; ++kd) {
                const int pd = (kd == 1) ? 0 : 1;
                const int dd = (kd == 0) ? 1 : 0;
#pragma unroll
                for (int kh = 0; kh < 3; ++kh) {
                    const int ph = (kh == 1) ? 0 : 1;
                    const int hh = (kh == 0) ? 1 : 0;
#pragma unroll
                    for (int kw = 0; kw < 3; ++kw) {
                        const int pw = (kw == 1) ? 0 : 1;
                        const int ww = (kw == 0) ? 1 : 0;
                        const float wt = wp[kd * 9 + kh * 3 + kw];   // lane-uniform -> SGPR
#pragma unroll
                        for (int v = 0; v < 2; ++v)
                            acc[v][pd][ph][pw] =
                                fmaf(wt, xr[c][dd][hh][v + ww], acc[v][pd][ph][pw]);
                    }
                }
            }
        }
        const float bco = bias[co];
#pragma unroll
        for (int v = 0; v < 2; ++v) {
            const float* a = &acc[v][0][0][0];
            const float m0 = fmaxf(fmaxf(a[0], a[1]), a[2]);   // -> v_max3
            const float m1 = fmaxf(fmaxf(a[3], a[4]), a[5]);
            const float m2 = fmaxf(fmaxf(a[6], a[7]), m0);
            pooled[v][co] = fmaxf(m1, m2) + bco;
        }
    }

    // channel softmax + subtract + swish + channel max, per voxel
    float res[2];
#pragma unroll
    for (int v = 0; v < 2; ++v) {
        float m = pooled[v][0];
#pragma unroll
        for (int co = 1; co < COUT; ++co) m = fmaxf(m, pooled[v][co]);
        float e[COUT];
        float s = 0.0f;
#pragma unroll
        for (int co = 0; co < COUT; ++co) {
            e[co] = __expf(pooled[v][co] - m);
            s += e[co];
        }
        const float inv = __builtin_amdgcn_rcpf(s);
        float best = -3.402823466e+38f;
#pragma unroll
        for (int co = 0; co < COUT; ++co) {
            const float z   = fmaf(e[co], inv, -sub[co]);
            const float sig = __builtin_amdgcn_rcpf(1.0f + __expf(-z));
            best = fmaxf(best, z * sig);
        }
        res[v] = best;
    }

    float* op = out + (((size_t)n * DHW + d) * DHW + h) * DHW + w0;
    *(float2*)op = make_float2(res[0], res[1]);      // coalesced 8B store
}

extern "C" void kernel_launch(void* const* d_in, const int* in_sizes, int n_in,
                              void* d_out, int out_size, void* d_ws, size_t ws_size,
                              hipStream_t stream) {
    const float* x   = (const float*)d_in[0];
    const float* w   = (const float*)d_in[1];
    const float* b   = (const float*)d_in[2];
    const float* sub = (const float*)d_in[3];
    float* out = (float*)d_out;

    dim3 block(32, 8, 1);                 // 32 w-pairs x 8 h-rows = 256 threads
    dim3 grid(DHW / 8, DHW, 4);           // (h-groups, d, n)
    fused_convt_pool_softmax_swish_max<<<grid, block, 0, stream>>>(x, w, b, sub, out);
}